// Round 7
// baseline (212.853 us; speedup 1.0000x reference)
//
#include <hip/hip_runtime.h>

#define SEQ    1024
#define BATCH  512
#define NTAGS  48
#define CH     8              // steps per register-staged emission chunk
#define NCHUNK (SEQ / CH)     // 128

// One wave per chain, bidirectional: forward alpha (t=1..511) and backward
// beta (u=1023..512) computed concurrently in the SAME wave; denominator =
// cf + cb + log(alpha_511 . beta_511). Two independent dependency chains
// interleave so readlane->FMA SGPR hazards of one chain are filled by the
// other chain's work. Lane j holds W column (forward) AND W row (backward).
// Emissions double-buffered in registers per direction; renorm every 4 steps
// pivots on the pre-update lane-0 broadcast (off the critical path).
__global__ __launch_bounds__(64) void crf_chain_kernel(
    const float* __restrict__ em,     // [SEQ,BATCH,NTAGS] f32
    const int*   __restrict__ tags,   // [SEQ,BATCH] int32
    const int*   __restrict__ mask,   // [SEQ,BATCH] int32
    const float* __restrict__ start_t,// [NTAGS]
    const float* __restrict__ end_t,  // [NTAGS]
    const float* __restrict__ trans,  // [NTAGS,NTAGS]
    float*       __restrict__ llh)    // [BATCH]
{
  const int b    = blockIdx.x;
  const int lane = threadIdx.x;          // single wave
  const bool act = lane < NTAGS;
  const int jj   = act ? lane : 0;

  __shared__ int smask[SEQ];

  // stage mask column; detect all-ones
  int myall = 1;
#pragma unroll
  for (int k = 0; k < SEQ / 64; ++k) {
    int t = lane + 64 * k;
    int v = mask[(size_t)t * BATCH + b];
    smask[t] = v;
    myall &= (v != 0) ? 1 : 0;
  }
  const bool allones = (__ballot(myall) == ~0ull);

  float wcol[NTAGS], wrow[NTAGS];
#pragma unroll
  for (int i = 0; i < NTAGS; ++i)
    wcol[i] = __expf(trans[i * NTAGS + jj]);   // W[i][jj]
#pragma unroll
  for (int i = 0; i < NTAGS; ++i)
    wrow[i] = __expf(trans[jj * NTAGS + i]);   // W[jj][i]

  const size_t strideT = (size_t)BATCH * NTAGS;
  const float* emcol   = em + (size_t)b * NTAGS + jj;

  float cf = 0.0f, cb = 0.0f;
  float a  = __expf(start_t[jj] + emcol[0]);   // forward alpha (lane jj)
  float Bv = __expf(end_t[jj]);                // backward beta

  float emA[CH], emB[CH], bmA[CH], bmB[CH];
  float exf, exb;

#define RLX(x, k) __int_as_float(__builtin_amdgcn_readlane(__float_as_int(x), (k)))

#define LOADCH(R, ci) do {                                            \
    const float* pp_ = emcol + (size_t)(ci) * CH * strideT;           \
    _Pragma("unroll")                                                 \
    for (int p_ = 0; p_ < CH; ++p_)                                   \
      (R)[p_] = pp_[(size_t)p_ * strideT];                            \
  } while (0)

  // ---- dual step: forward position i (t=TF0+i), backward pb=7-i (u=UB0+pb)
#define DSTEP(i, FC, FN, BC, BN, TF0, UB0, MASKED) do {               \
    const int pb_ = 7 - (i);                                          \
    float gm_ = Bv * exb;                      /* gamma = beta*ex_u */\
    float gf_[NTAGS], gb_[NTAGS];                                     \
    float accf_[4] = {0.f,0.f,0.f,0.f};                               \
    float accb_[4] = {0.f,0.f,0.f,0.f};                               \
    _Pragma("unroll") for (int q_ = 0; q_ < 8; ++q_)                  \
      { gf_[q_] = RLX(a, q_); gb_[q_] = RLX(gm_, q_); }               \
    __builtin_amdgcn_sched_barrier(0);                                \
    float rmf_ = 0.f, rmb_ = 0.f;                                     \
    if (((i) & 3) == 3) { rmf_ = __builtin_amdgcn_rcpf(gf_[0]);       \
                          rmb_ = __builtin_amdgcn_rcpf(gb_[0]); }     \
    _Pragma("unroll") for (int s_ = 8; s_ <= 40; s_ += 8) {           \
      _Pragma("unroll") for (int q_ = s_; q_ < s_ + 8; ++q_)          \
        { gf_[q_] = RLX(a, q_); gb_[q_] = RLX(gm_, q_); }             \
      _Pragma("unroll") for (int q_ = s_ - 8; q_ < s_; ++q_) {        \
        accf_[q_ & 3] = fmaf(gf_[q_], wcol[q_], accf_[q_ & 3]);       \
        accb_[q_ & 3] = fmaf(gb_[q_], wrow[q_], accb_[q_ & 3]);       \
      }                                                               \
      __builtin_amdgcn_sched_barrier(0);                              \
    }                                                                 \
    _Pragma("unroll") for (int q_ = 40; q_ < 48; ++q_) {              \
      accf_[q_ & 3] = fmaf(gf_[q_], wcol[q_], accf_[q_ & 3]);         \
      accb_[q_ & 3] = fmaf(gb_[q_], wrow[q_], accb_[q_ & 3]);         \
    }                                                                 \
    float sf_ = (accf_[0] + accf_[1]) + (accf_[2] + accf_[3]);        \
    float sb_ = (accb_[0] + accb_[1]) + (accb_[2] + accb_[3]);        \
    float naf_ = sf_ * exf;                                           \
    float nb_  = sb_;                                                 \
    if (MASKED) {                                                     \
      int mkf_ = smask[(TF0) + (i)];                                  \
      int mkb_ = smask[(UB0) + pb_];                                  \
      naf_ = mkf_ ? naf_ : a;                                         \
      nb_  = mkb_ ? nb_  : Bv;                                        \
    }                                                                 \
    if (((i) & 3) == 3) {                                             \
      cf += __logf(gf_[0]);  a  = naf_ * rmf_;                        \
      cb += __logf(gb_[0]);  Bv = nb_  * rmb_;                        \
    } else { a = naf_; Bv = nb_; }                                    \
    exf = __expf(((i) < 7) ? (FC)[(i) + 1] : (FN)[0]);                \
    if ((i) < 7) exb = __expf((BC)[6 - (i)]);                         \
    else         exb = __expf((BN)[7]);                               \
  } while (0)

  // forward-only step (prologue chunk 0)
#define FSTEP(p, CUR, NXT, MASKED) do {                               \
    float gf_[NTAGS];                                                 \
    float accf_[4] = {0.f,0.f,0.f,0.f};                               \
    _Pragma("unroll") for (int q_ = 0; q_ < 8; ++q_)                  \
      gf_[q_] = RLX(a, q_);                                           \
    __builtin_amdgcn_sched_barrier(0);                                \
    float rmf_ = 0.f;                                                 \
    if (((p) & 3) == 3) rmf_ = __builtin_amdgcn_rcpf(gf_[0]);         \
    _Pragma("unroll") for (int s_ = 8; s_ <= 40; s_ += 8) {           \
      _Pragma("unroll") for (int q_ = s_; q_ < s_ + 8; ++q_)          \
        gf_[q_] = RLX(a, q_);                                         \
      _Pragma("unroll") for (int q_ = s_ - 8; q_ < s_; ++q_)          \
        accf_[q_ & 3] = fmaf(gf_[q_], wcol[q_], accf_[q_ & 3]);       \
      __builtin_amdgcn_sched_barrier(0);                              \
    }                                                                 \
    _Pragma("unroll") for (int q_ = 40; q_ < 48; ++q_)                \
      accf_[q_ & 3] = fmaf(gf_[q_], wcol[q_], accf_[q_ & 3]);         \
    float sf_ = (accf_[0] + accf_[1]) + (accf_[2] + accf_[3]);        \
    float naf_ = sf_ * exf;                                           \
    if (MASKED) { int mk_ = smask[(p)]; naf_ = mk_ ? naf_ : a; }      \
    if (((p) & 3) == 3) { cf += __logf(gf_[0]); a = naf_ * rmf_; }    \
    else a = naf_;                                                    \
    exf = __expf(((p) < 7) ? (CUR)[(p) + 1] : (NXT)[0]);              \
  } while (0)

  // backward-only step (epilogue chunk 64): i ascending, pb=7-i, u=512+pb
#define BSTEP(i, CUR, MASKED) do {                                    \
    const int pb_ = 7 - (i);                                          \
    float gm_ = Bv * exb;                                             \
    float gb_[NTAGS];                                                 \
    float accb_[4] = {0.f,0.f,0.f,0.f};                               \
    _Pragma("unroll") for (int q_ = 0; q_ < 8; ++q_)                  \
      gb_[q_] = RLX(gm_, q_);                                         \
    __builtin_amdgcn_sched_barrier(0);                                \
    float rmb_ = 0.f;                                                 \
    if (((i) & 3) == 3) rmb_ = __builtin_amdgcn_rcpf(gb_[0]);         \
    _Pragma("unroll") for (int s_ = 8; s_ <= 40; s_ += 8) {           \
      _Pragma("unroll") for (int q_ = s_; q_ < s_ + 8; ++q_)          \
        gb_[q_] = RLX(gm_, q_);                                       \
      _Pragma("unroll") for (int q_ = s_ - 8; q_ < s_; ++q_)          \
        accb_[q_ & 3] = fmaf(gb_[q_], wrow[q_], accb_[q_ & 3]);       \
      __builtin_amdgcn_sched_barrier(0);                              \
    }                                                                 \
    _Pragma("unroll") for (int q_ = 40; q_ < 48; ++q_)                \
      accb_[q_ & 3] = fmaf(gb_[q_], wrow[q_], accb_[q_ & 3]);         \
    float sb_ = (accb_[0] + accb_[1]) + (accb_[2] + accb_[3]);        \
    float nb_ = sb_;                                                  \
    if (MASKED) { int mk_ = smask[512 + pb_]; nb_ = mk_ ? nb_ : Bv; } \
    if (((i) & 3) == 3) { cb += __logf(gb_[0]); Bv = nb_ * rmb_; }    \
    else Bv = nb_;                                                    \
    if ((i) < 7) exb = __expf((CUR)[6 - (i)]);                        \
  } while (0)

#define DUALCHUNK(FC, FN, BC, BN, k, MASKED) do {                     \
    int fn_ = ((k) + 1 <= 63) ? (k) + 1 : 63;                         \
    LOADCH(FN, fn_);                                                  \
    LOADCH(BN, 127 - (k));                                            \
    _Pragma("unroll")                                                 \
    for (int i_ = 0; i_ < CH; ++i_)                                   \
      DSTEP(i_, FC, FN, BC, BN, (k) * CH, (128 - (k)) * CH, MASKED);  \
  } while (0)

  // prologue: fwd chunk0 + bwd chunk127 staged; exf for t=1, exb for u=1023
  LOADCH(emA, 0);
  LOADCH(bmA, 127);
  exf = __expf(emA[1]);
  exb = __expf(bmA[7]);

#define CHAIN_LOOP(MASKED) do {                                       \
    LOADCH(emB, 1);                                                   \
    _Pragma("unroll")                                                 \
    for (int p_ = 1; p_ < CH; ++p_) FSTEP(p_, emA, emB, MASKED);      \
    for (int k = 1; k <= 61; k += 2) {                                \
      DUALCHUNK(emB, emA, bmA, bmB, k,     MASKED);                   \
      DUALCHUNK(emA, emB, bmB, bmA, k + 1, MASKED);                   \
    }                                                                 \
    DUALCHUNK(emB, emA, bmA, bmB, 63, MASKED);                        \
    _Pragma("unroll")                                                 \
    for (int i_ = 0; i_ < CH; ++i_) BSTEP(i_, bmB, MASKED);           \
  } while (0)

  if (allones) CHAIN_LOOP(0);
  else         CHAIN_LOOP(1);

  // denominator: cf + cb + log(alpha_511 . beta_511)
  float v = act ? a * Bv : 0.0f;
#pragma unroll
  for (int off = 32; off > 0; off >>= 1)
    v += __shfl_xor(v, off);
  float den = cf + cb + __logf(v);

  // numerator: tag-path score; lanes parallel over t
  float np = 0.0f;
  int   mcount = 0;
  for (int t = lane; t < SEQ; t += 64) {
    int tag_t = tags[(size_t)t * BATCH + b];
    tag_t = min(max(tag_t, 0), NTAGS - 1);
    int mk = smask[t];
    float e = em[(size_t)t * strideT + (size_t)b * NTAGS + tag_t];
    if (t == 0) {
      np += start_t[tag_t] + e;
    } else {
      int tag_p = tags[(size_t)(t - 1) * BATCH + b];
      tag_p = min(max(tag_p, 0), NTAGS - 1);
      np += (trans[tag_p * NTAGS + tag_t] + e) * (float)mk;
    }
    mcount += (mk != 0) ? 1 : 0;
  }
#pragma unroll
  for (int off = 32; off > 0; off >>= 1) {
    np     += __shfl_xor(np, off);
    mcount += __shfl_xor(mcount, off);
  }
  int last_idx = min(max(mcount - 1, 0), SEQ - 1);
  int tag_last = tags[(size_t)last_idx * BATCH + b];
  tag_last = min(max(tag_last, 0), NTAGS - 1);
  float num = np + end_t[tag_last];

  if (lane == 0) llh[b] = num - den;
}

__global__ __launch_bounds__(64) void crf_reduce_kernel(
    const float* __restrict__ llh, float* __restrict__ out)
{
  const int lane = threadIdx.x;
  float v = 0.0f;
#pragma unroll
  for (int k = 0; k < BATCH / 64; ++k)
    v += llh[lane + 64 * k];
#pragma unroll
  for (int off = 32; off > 0; off >>= 1)
    v += __shfl_xor(v, off);
  if (lane == 0) out[0] = v * (1.0f / (float)BATCH);
}

extern "C" void kernel_launch(void* const* d_in, const int* in_sizes, int n_in,
                              void* d_out, int out_size, void* d_ws, size_t ws_size,
                              hipStream_t stream) {
  const float* em   = (const float*)d_in[0];
  const int*   tg   = (const int*)  d_in[1];
  const int*   mask = (const int*)  d_in[2];
  const float* st   = (const float*)d_in[3];
  const float* en   = (const float*)d_in[4];
  const float* tr   = (const float*)d_in[5];
  float* llh = (float*)d_ws;

  crf_chain_kernel<<<BATCH, 64, 0, stream>>>(em, tg, mask, st, en, tr, llh);
  crf_reduce_kernel<<<1, 64, 0, stream>>>(llh, (float*)d_out);
}

// Round 8
// 122.813 us; speedup vs baseline: 1.7331x; 1.7331x over previous
//
#include <hip/hip_runtime.h>

#define SEQ    1024
#define BATCH  512
#define NTAGS  48
#define CH     8

// Bidirectional split ACROSS waves: blocks 0..511 compute the forward chain
// alpha_t (t=1..511) for chain b; blocks 512..1023 compute the backward chain
// beta_u (u=1023..512, transposed recurrence on W rows). Each wave runs ~512
// steps of the proven r6 step (48 readlane broadcasts in 3 groups + 48 FMA,
// renorm every 4 steps on the pre-update lane-0 pivot). A combine kernel
// forms den = cf + cb + log(alpha . beta) and the mean.
__global__ __launch_bounds__(64) void crf_dir_kernel(
    const float* __restrict__ em,     // [SEQ,BATCH,NTAGS] f32
    const int*   __restrict__ tags,   // [SEQ,BATCH] int32
    const int*   __restrict__ mask,   // [SEQ,BATCH] int32
    const float* __restrict__ start_t,
    const float* __restrict__ end_t,
    const float* __restrict__ trans,  // [NTAGS,NTAGS]
    float*       __restrict__ alpha,  // [BATCH,NTAGS]
    float*       __restrict__ beta,   // [BATCH,NTAGS]
    float*       __restrict__ cfb,    // [BATCH]
    float*       __restrict__ cbb,    // [BATCH]
    float*       __restrict__ numb)   // [BATCH]
{
  const int bid  = blockIdx.x;
  const int b    = bid & (BATCH - 1);
  const int dir  = bid >> 9;             // 0 = forward, 1 = backward
  const int lane = threadIdx.x;
  const bool act = lane < NTAGS;
  const int jj   = act ? lane : 0;

  __shared__ int smask[SEQ];
  int myall = 1;
#pragma unroll
  for (int k = 0; k < SEQ / 64; ++k) {
    int t = lane + 64 * k;
    int v = mask[(size_t)t * BATCH + b];
    smask[t] = v;
    myall &= (v != 0) ? 1 : 0;
  }
  const bool allones = (__ballot(myall) == ~0ull);

  const size_t strideT = (size_t)BATCH * NTAGS;
  const float* emcol   = em + (size_t)b * NTAGS + jj;

#define RLX(x, k) __int_as_float(__builtin_amdgcn_readlane(__float_as_int(x), (k)))

#define LOADCH(R, ci) do {                                            \
    const float* pp_ = emcol + (size_t)(ci) * CH * strideT;           \
    _Pragma("unroll")                                                 \
    for (int p_ = 0; p_ < CH; ++p_)                                   \
      (R)[p_] = pp_[(size_t)p_ * strideT];                            \
  } while (0)

  if (dir == 0) {
    // ================= FORWARD: t = 1..511 =================
    float wcol[NTAGS];
#pragma unroll
    for (int i = 0; i < NTAGS; ++i)
      wcol[i] = __expf(trans[i * NTAGS + jj]);     // W[i][jj]

    float cf = 0.0f;
    float a  = __expf(start_t[jj] + emcol[0]);
    float emA[CH], emB[CH], exf;

#define FMAGF(G, base)                                                \
    _Pragma("unroll")                                                 \
    for (int q_ = 0; q_ < 16; ++q_)                                   \
      acc_[q_ & 7] = fmaf((G)[q_], wcol[(base) + q_], acc_[q_ & 7]);

#define FSTEP(p, CUR, NXT, T0, MASKED) do {                           \
    float g0_[16], g1_[16], g2_[16];                                  \
    float acc_[8];                                                    \
    _Pragma("unroll") for (int q_ = 0; q_ < 8;  ++q_) acc_[q_] = 0.f; \
    _Pragma("unroll") for (int q_ = 0; q_ < 16; ++q_) g0_[q_] = RLX(a, q_);\
    __builtin_amdgcn_sched_barrier(0);                                \
    float rm_ = 0.f;                                                  \
    if (((p) & 3) == 3) rm_ = __builtin_amdgcn_rcpf(g0_[0]);          \
    _Pragma("unroll") for (int q_ = 0; q_ < 16; ++q_) g1_[q_] = RLX(a, 16 + q_);\
    FMAGF(g0_, 0);                                                    \
    __builtin_amdgcn_sched_barrier(0);                                \
    _Pragma("unroll") for (int q_ = 0; q_ < 16; ++q_) g2_[q_] = RLX(a, 32 + q_);\
    FMAGF(g1_, 16);                                                   \
    __builtin_amdgcn_sched_barrier(0);                                \
    FMAGF(g2_, 32);                                                   \
    float s_ = ((acc_[0] + acc_[1]) + (acc_[2] + acc_[3]))            \
             + ((acc_[4] + acc_[5]) + (acc_[6] + acc_[7]));           \
    float na_ = s_ * exf;                                             \
    if (((p) & 3) == 3) {                                             \
      cf += __logf(g0_[0]);                                           \
      na_ *= rm_;                                                     \
      if (MASKED) { int mk_ = smask[(T0) + (p)];                      \
                    a = mk_ ? na_ : a * rm_; }                        \
      else a = na_;                                                   \
    } else {                                                          \
      if (MASKED) { int mk_ = smask[(T0) + (p)]; a = mk_ ? na_ : a; } \
      else a = na_;                                                   \
    }                                                                 \
    exf = __expf(((p) < CH - 1) ? (CUR)[(p) + 1] : (NXT)[0]);         \
  } while (0)

#define CHUNKF(CUR, NXT, ci, PSTART, MASKED) do {                     \
    int cin_ = ((ci) + 1 < 64) ? (ci) + 1 : 63;                       \
    LOADCH(NXT, cin_);                                                \
    _Pragma("unroll")                                                 \
    for (int p_ = (PSTART); p_ < CH; ++p_)                            \
      FSTEP(p_, CUR, NXT, (ci) * CH, MASKED);                         \
  } while (0)

    LOADCH(emA, 0);
    exf = __expf(emA[1]);

#define FLOOP(M) do {                                                 \
    CHUNKF(emA, emB, 0, 1, M);                                        \
    for (int ci = 1; ci <= 61; ci += 2) {                             \
      CHUNKF(emB, emA, ci,     0, M);                                 \
      CHUNKF(emA, emB, ci + 1, 0, M);                                 \
    }                                                                 \
    CHUNKF(emB, emA, 63, 0, M);                                       \
  } while (0)

    if (allones) FLOOP(0);
    else         FLOOP(1);

    if (act) alpha[b * NTAGS + lane] = a;
    if (lane == 0) cfb[b] = cf;

    // numerator: tag-path score; lanes parallel over t
    float np = 0.0f;
    int   mcount = 0;
    for (int t = lane; t < SEQ; t += 64) {
      int tag_t = tags[(size_t)t * BATCH + b];
      tag_t = min(max(tag_t, 0), NTAGS - 1);
      int mk = smask[t];
      float e = em[(size_t)t * strideT + (size_t)b * NTAGS + tag_t];
      if (t == 0) {
        np += start_t[tag_t] + e;
      } else {
        int tag_p = tags[(size_t)(t - 1) * BATCH + b];
        tag_p = min(max(tag_p, 0), NTAGS - 1);
        np += (trans[tag_p * NTAGS + tag_t] + e) * (float)mk;
      }
      mcount += (mk != 0) ? 1 : 0;
    }
#pragma unroll
    for (int off = 32; off > 0; off >>= 1) {
      np     += __shfl_xor(np, off);
      mcount += __shfl_xor(mcount, off);
    }
    int last_idx = min(max(mcount - 1, 0), SEQ - 1);
    int tag_last = tags[(size_t)last_idx * BATCH + b];
    tag_last = min(max(tag_last, 0), NTAGS - 1);
    if (lane == 0) numb[b] = np + end_t[tag_last];

  } else {
    // ================= BACKWARD: u = 1023..512 =================
    float wrow[NTAGS];
#pragma unroll
    for (int i = 0; i < NTAGS; ++i)
      wrow[i] = __expf(trans[jj * NTAGS + i]);     // W[jj][i]

    float cb = 0.0f;
    float Bv = __expf(end_t[jj]);
    float bmA[CH], bmB[CH], exb;

#define FMAGB(G, base)                                                \
    _Pragma("unroll")                                                 \
    for (int q_ = 0; q_ < 16; ++q_)                                   \
      acc_[q_ & 7] = fmaf((G)[q_], wrow[(base) + q_], acc_[q_ & 7]);

#define BSTEP(i, CUR, NXT, U0, MASKED) do {                           \
    const int pb_ = CH - 1 - (i);                                     \
    float gm_ = Bv * exb;                                             \
    float g0_[16], g1_[16], g2_[16];                                  \
    float acc_[8];                                                    \
    _Pragma("unroll") for (int q_ = 0; q_ < 8;  ++q_) acc_[q_] = 0.f; \
    _Pragma("unroll") for (int q_ = 0; q_ < 16; ++q_) g0_[q_] = RLX(gm_, q_);\
    __builtin_amdgcn_sched_barrier(0);                                \
    float rm_ = 0.f;                                                  \
    if (((i) & 3) == 3) rm_ = __builtin_amdgcn_rcpf(g0_[0]);          \
    _Pragma("unroll") for (int q_ = 0; q_ < 16; ++q_) g1_[q_] = RLX(gm_, 16 + q_);\
    FMAGB(g0_, 0);                                                    \
    __builtin_amdgcn_sched_barrier(0);                                \
    _Pragma("unroll") for (int q_ = 0; q_ < 16; ++q_) g2_[q_] = RLX(gm_, 32 + q_);\
    FMAGB(g1_, 16);                                                   \
    __builtin_amdgcn_sched_barrier(0);                                \
    FMAGB(g2_, 32);                                                   \
    float s_ = ((acc_[0] + acc_[1]) + (acc_[2] + acc_[3]))            \
             + ((acc_[4] + acc_[5]) + (acc_[6] + acc_[7]));           \
    float nb_ = s_;                                                   \
    if (MASKED) { int mk_ = smask[(U0) + pb_]; nb_ = mk_ ? nb_ : Bv; }\
    if (((i) & 3) == 3) {                                             \
      cb += __logf(g0_[0]);                                           \
      Bv = nb_ * rm_;                                                 \
    } else Bv = nb_;                                                  \
    exb = __expf(((i) < CH - 1) ? (CUR)[pb_ - 1] : (NXT)[CH - 1]);    \
  } while (0)

#define CHUNKB(CUR, NXT, k, MASKED) do {                              \
    int kn_ = ((k) - 1 > 64) ? (k) - 1 : 64;                          \
    LOADCH(NXT, kn_);                                                 \
    _Pragma("unroll")                                                 \
    for (int i_ = 0; i_ < CH; ++i_)                                   \
      BSTEP(i_, CUR, NXT, (k) * CH, MASKED);                          \
  } while (0)

    LOADCH(bmA, 127);
    exb = __expf(bmA[CH - 1]);       // exp(em[1023])

#define BLOOP(M) do {                                                 \
    CHUNKB(bmA, bmB, 127, M);                                         \
    for (int k = 126; k >= 66; k -= 2) {                              \
      CHUNKB(bmB, bmA, k,     M);                                     \
      CHUNKB(bmA, bmB, k - 1, M);                                     \
    }                                                                 \
    CHUNKB(bmB, bmA, 64, M);                                          \
  } while (0)

    if (allones) BLOOP(0);
    else         BLOOP(1);

    if (act) beta[b * NTAGS + lane] = Bv;
    if (lane == 0) cbb[b] = cb;
  }
}

// 512 threads, one per chain: den = cf+cb+log(alpha.beta); mean of num-den.
__global__ __launch_bounds__(512) void crf_combine_kernel(
    const float* __restrict__ alpha, const float* __restrict__ beta,
    const float* __restrict__ cfb,   const float* __restrict__ cbb,
    const float* __restrict__ numb,  float* __restrict__ out)
{
  const int tid = threadIdx.x;       // 0..511 = chain
  float dot = 0.0f;
#pragma unroll
  for (int j = 0; j < NTAGS; j += 4) {
    float4 av = *(const float4*)&alpha[tid * NTAGS + j];
    float4 bv = *(const float4*)&beta [tid * NTAGS + j];
    dot += av.x * bv.x + av.y * bv.y + av.z * bv.z + av.w * bv.w;
  }
  float den = cfb[tid] + cbb[tid] + __logf(dot);
  float v   = numb[tid] - den;

#pragma unroll
  for (int off = 32; off > 0; off >>= 1)
    v += __shfl_xor(v, off);

  __shared__ float sw[8];
  if ((tid & 63) == 0) sw[tid >> 6] = v;
  __syncthreads();
  if (tid == 0) {
    float s = 0.0f;
#pragma unroll
    for (int w = 0; w < 8; ++w) s += sw[w];
    out[0] = s * (1.0f / (float)BATCH);
  }
}

extern "C" void kernel_launch(void* const* d_in, const int* in_sizes, int n_in,
                              void* d_out, int out_size, void* d_ws, size_t ws_size,
                              hipStream_t stream) {
  const float* em   = (const float*)d_in[0];
  const int*   tg   = (const int*)  d_in[1];
  const int*   mask = (const int*)  d_in[2];
  const float* st   = (const float*)d_in[3];
  const float* en   = (const float*)d_in[4];
  const float* tr   = (const float*)d_in[5];

  float* ws    = (float*)d_ws;
  float* alpha = ws;                              // 512*48
  float* beta  = ws + BATCH * NTAGS;              // 512*48
  float* cfb   = ws + 2 * BATCH * NTAGS;          // 512
  float* cbb   = cfb + BATCH;                     // 512
  float* numb  = cbb + BATCH;                     // 512

  crf_dir_kernel<<<2 * BATCH, 64, 0, stream>>>(em, tg, mask, st, en, tr,
                                               alpha, beta, cfb, cbb, numb);
  crf_combine_kernel<<<1, 512, 0, stream>>>(alpha, beta, cfb, cbb, numb,
                                            (float*)d_out);
}